// Round 16
// baseline (202.438 us; speedup 1.0000x reference)
//
#include <hip/hip_runtime.h>
#include <math.h>

typedef __attribute__((ext_vector_type(8))) short bf16x8;   // 8 bf16 = 4 VGPRs
typedef __attribute__((ext_vector_type(4))) short bf16x4;   // 4 bf16 = 2 VGPRs
typedef __attribute__((ext_vector_type(4))) float f32x4;
typedef unsigned short u16;

namespace {
constexpr int BATCH = 4, SEQ = 2048, CDIM = 768, NH = 12, HD = 64;
constexpr int MROWS = BATCH * SEQ;  // 8192
constexpr int KD = CDIM;            // 768
// fold attention scale (1/8) * log2(e) into Q so softmax uses exp2 directly
constexpr float QSCALE = 0.125f * 1.44269504088896f;
}

__device__ __forceinline__ u16 f2bf(float f) {  // RNE float->bf16 (finite inputs)
  unsigned x = __float_as_uint(f);
  return (u16)((x + 0x7fffu + ((x >> 16) & 1u)) >> 16);
}

// packed f32x2 -> bf16x2 (lo=a, hi=b — verified by v5/v6/v7b passing kernels)
__device__ __forceinline__ unsigned pk2bf(float a, float b) {
  unsigned r;
  asm("v_cvt_pk_bf16_f32 %0, %1, %2" : "=v"(r) : "v"(a), "v"(b));
  return r;
}

// exp2 via builtin (R5/R6 A/B: builtin beats inline-asm — scheduler freedom)
#if defined(__has_builtin)
#if __has_builtin(__builtin_amdgcn_exp2f)
#define EXP2(x) __builtin_amdgcn_exp2f(x)
#endif
#endif
#ifndef EXP2
#define EXP2(x) exp2f(x)
#endif

// global_load_lds: 16B per lane, LDS dst = wave-uniform base + lane*16
#define GLD16(gp, lp)                                                        \
  __builtin_amdgcn_global_load_lds(                                          \
      (const __attribute__((address_space(1))) void*)(gp),                   \
      (__attribute__((address_space(3))) void*)(lp), 16, 0, 0)

// ---------------------------------------------------------------------------
// Pre-pass: fp32 -> bf16 for x, w_qkv, w_out
// ---------------------------------------------------------------------------
__global__ void convert_bf16(const float* __restrict__ x, u16* __restrict__ xb, int nx4,
                             const float* __restrict__ w1, u16* __restrict__ w1b, int n14,
                             const float* __restrict__ w2, u16* __restrict__ w2b, int n24) {
  const int stride = gridDim.x * blockDim.x;
  const int t0 = blockIdx.x * blockDim.x + threadIdx.x;
  for (int i = t0; i < nx4; i += stride) {
    float4 v = ((const float4*)x)[i];
    ushort4 o; o.x = f2bf(v.x); o.y = f2bf(v.y); o.z = f2bf(v.z); o.w = f2bf(v.w);
    ((ushort4*)xb)[i] = o;
  }
  for (int i = t0; i < n14; i += stride) {
    float4 v = ((const float4*)w1)[i];
    ushort4 o; o.x = f2bf(v.x); o.y = f2bf(v.y); o.z = f2bf(v.z); o.w = f2bf(v.w);
    ((ushort4*)w1b)[i] = o;
  }
  for (int i = t0; i < n24; i += stride) {
    float4 v = ((const float4*)w2)[i];
    ushort4 o; o.x = f2bf(v.x); o.y = f2bf(v.y); o.z = f2bf(v.z); o.w = f2bf(v.w);
    ((ushort4*)w2b)[i] = o;
  }
}

// ---------------------------------------------------------------------------
// bf16 MFMA GEMM (R7/R12 form — best across 5 structural variants; 16 w/CU).
// ONLY change this round: MODE 0's V epilogue stores keys PERMUTED within
// each 32-key group: pos(k) = 8*((k>>2)&3) + 4*((k>>4)&1) + (k&3). This makes
// attn's PV V-fragment a single conflict-free b128 read (was 2x 4-way-
// aliased b64). Stores stay within the same 64B segment (coalescing intact).
// ---------------------------------------------------------------------------
template <int MODE>
__global__ __launch_bounds__(512, 4) void gemm_bf16(
    const u16* __restrict__ A, const u16* __restrict__ Bw,
    const float* __restrict__ bias, float* __restrict__ outf,
    u16* __restrict__ qws, u16* __restrict__ kws, u16* __restrict__ vws) {
  __shared__ u16 smem[2 * 2 * 128 * 64];  // [buf][As|Bs], 64 KiB
  const int t = threadIdx.x;
  const int w = t >> 6, l = t & 63, g = l >> 4, li = l & 15;
  const int wm = w >> 1, wn = w & 1;  // 4 x 2 wave grid
  const int lin = blockIdx.x;
  const int rowb = ((lin & 7) << 3) | ((lin >> 3) & 7);
  const int colb = lin >> 6;
  const int row0 = rowb * 128, col0 = colb * 128;

  const int srow = w * 16 + (l >> 3);
  const int skc = (l & 7) ^ (l >> 3);
  const u16* gA = A + (size_t)(row0 + srow) * KD + skc * 8;
  const u16* gB = Bw + (size_t)(col0 + srow) * KD + skc * 8;

  f32x4 acc[2][4];
#pragma unroll
  for (int a = 0; a < 2; ++a)
#pragma unroll
    for (int c = 0; c < 4; ++c) acc[a][c] = {0.f, 0.f, 0.f, 0.f};

#define GSTAGE(kt_, buf_)                                                     \
  do {                                                                        \
    const int k0_ = (kt_) * 64;                                               \
    u16* As_ = smem + (buf_) * (2 * 128 * 64);                                \
    u16* Bs_ = As_ + 128 * 64;                                                \
    _Pragma("unroll")                                                         \
    for (int j = 0; j < 2; ++j) {                                             \
      GLD16(gA + (size_t)8 * j * KD + k0_, &As_[(w * 16 + 8 * j) * 64]);      \
      GLD16(gB + (size_t)8 * j * KD + k0_, &Bs_[(w * 16 + 8 * j) * 64]);      \
    }                                                                         \
  } while (0)

  constexpr int NK = KD / 64;  // 12
  GSTAGE(0, 0);
  GSTAGE(1, 1);
  asm volatile("s_waitcnt vmcnt(4)" ::: "memory");
  __builtin_amdgcn_sched_barrier(0);
  __builtin_amdgcn_s_barrier();
  __builtin_amdgcn_sched_barrier(0);

  for (int kt = 0; kt < NK; ++kt) {
    const int cur = kt & 1;
    const u16* AsC = smem + cur * (2 * 128 * 64);
    const u16* BsC = AsC + 128 * 64;

    bf16x8 af[2][2], bfr[4][2];
#pragma unroll
    for (int mi = 0; mi < 2; ++mi) {
      const int r = wm * 32 + mi * 16 + li;
#pragma unroll
      for (int ks = 0; ks < 2; ++ks)
        af[mi][ks] = *(const bf16x8*)&AsC[r * 64 + (((ks * 4 + g) ^ (li & 7)) * 8)];
    }
#pragma unroll
    for (int ni = 0; ni < 4; ++ni) {
      const int r = wn * 64 + ni * 16 + li;
#pragma unroll
      for (int ks = 0; ks < 2; ++ks)
        bfr[ni][ks] = *(const bf16x8*)&BsC[r * 64 + (((ks * 4 + g) ^ (li & 7)) * 8)];
    }
    __builtin_amdgcn_s_setprio(1);
#pragma unroll
    for (int ni = 0; ni < 4; ++ni)
#pragma unroll
      for (int mi = 0; mi < 2; ++mi) {
        acc[mi][ni] = __builtin_amdgcn_mfma_f32_16x16x32_bf16(af[mi][0], bfr[ni][0], acc[mi][ni], 0, 0, 0);
        acc[mi][ni] = __builtin_amdgcn_mfma_f32_16x16x32_bf16(af[mi][1], bfr[ni][1], acc[mi][ni], 0, 0, 0);
      }
    __builtin_amdgcn_s_setprio(0);

    if (kt + 1 < NK) {
      asm volatile("s_waitcnt vmcnt(0)" ::: "memory");
      __builtin_amdgcn_sched_barrier(0);
      __builtin_amdgcn_s_barrier();
      __builtin_amdgcn_sched_barrier(0);
      if (kt + 2 < NK) GSTAGE(kt + 2, cur);
    }
  }
#undef GSTAGE

  float bsr[4];
#pragma unroll
  for (int ni = 0; ni < 4; ++ni) bsr[ni] = bias[col0 + wn * 64 + ni * 16 + li];
  const int bidx = row0 >> 11;
  const int nseq0 = row0 & (SEQ - 1);

  __syncthreads();  // done with As/Bs; reuse smem for C staging

  if (MODE == 1) {
    float* Cf = (float*)smem;
#pragma unroll
    for (int p = 0; p < 4; ++p) {
      if (wm == p) {
#pragma unroll
        for (int mi = 0; mi < 2; ++mi)
#pragma unroll
          for (int ni = 0; ni < 4; ++ni)
#pragma unroll
            for (int i = 0; i < 4; ++i)
              Cf[(mi * 16 + 4 * g + i) * 132 + wn * 64 + ni * 16 + li] =
                  acc[mi][ni][i] + bsr[ni];
      }
      __syncthreads();
#pragma unroll
      for (int j = 0; j < 2; ++j) {
        const int fid = t + 512 * j;           // 0..1023
        const int r = fid >> 5, c4 = (fid & 31) * 4;
        *(float4*)(outf + (size_t)(row0 + p * 32 + r) * CDIM + col0 + c4) =
            *(const float4*)&Cf[r * 132 + c4];
      }
      __syncthreads();
    }
  } else {
#pragma unroll
    for (int hc = 0; hc < 2; ++hc) {
      const int nb = col0 + hc * 64;
      const int s = nb / CDIM;
      const int h = (nb % CDIM) / HD;
      if (wn == hc) {
        if (s < 2) {
          const float qs = (s == 0) ? QSCALE : 1.f;
#pragma unroll
          for (int mi = 0; mi < 2; ++mi)
#pragma unroll
            for (int ni = 0; ni < 4; ++ni)
#pragma unroll
              for (int i = 0; i < 4; ++i)
                smem[(wm * 32 + mi * 16 + 4 * g + i) * 72 + ni * 16 + li] =
                    f2bf((acc[mi][ni][i] + bsr[ni]) * qs);
        } else {
#pragma unroll
          for (int mi = 0; mi < 2; ++mi)
#pragma unroll
            for (int ni = 0; ni < 4; ++ni)
#pragma unroll
              for (int i = 0; i < 4; ++i)
                smem[(ni * 16 + li) * 136 + wm * 32 + mi * 16 + 4 * g + i] =
                    f2bf(acc[mi][ni][i] + bsr[ni]);
        }
      }
      __syncthreads();
      if (s < 2) {
        u16* dst = (s == 0 ? qws : kws) + ((size_t)(bidx * NH + h) * SEQ + nseq0) * HD;
        const int r = t >> 3, c = (t & 7) * 8;   // r 0..63
#pragma unroll
        for (int rd = 0; rd < 2; ++rd)
          *(uint4*)(dst + (size_t)(r + 64 * rd) * HD + c) =
              *(const uint4*)&smem[(r + 64 * rd) * 72 + c];
      } else {
        // V store with intra-32-key permutation: position-chunk c holds keys
        // {kbase..kbase+3} U {kbase+16..kbase+19}, kbase = (c&~31) + 4*((c>>3)&3)
        u16* dst = vws + (size_t)(bidx * NH + h) * HD * SEQ + nseq0;
        const int d = t >> 4, c = (t & 15) * 8;  // d 0..31, c = position offset
        const int kbase = (c & ~31) + ((c >> 3) & 3) * 4;
#pragma unroll
        for (int rd = 0; rd < 2; ++rd) {
          const u16* src = &smem[(d + 32 * rd) * 136 + kbase];
          uint2 lo = *(const uint2*)src;         // keys kbase..+3
          uint2 hi = *(const uint2*)(src + 16);  // keys kbase+16..+19
          uint4 st; st.x = lo.x; st.y = lo.y; st.z = hi.x; st.w = hi.y;
          *(uint4*)(dst + (size_t)(d + 32 * rd) * SEQ + c) = st;
        }
      }
      __syncthreads();
    }
  }
}

// ---------------------------------------------------------------------------
// Flash attention v6.2: v6.1 with the PV V-fragment as a SINGLE b128 read —
// valid because V's global key order is now permuted (see gemm MODE 0) so the
// bijection's 8 keys {16(j>>2)+4g+(j&3)} sit at contiguous positions 8g..8g+7.
// Read chunk (ks*4+g)^(d&7): same conflict-free structure as the K read.
// Everything else byte-identical to R12/R15 (measured 68-70 us).
// ---------------------------------------------------------------------------
__global__ __launch_bounds__(256, 3) void attn_mfma(
    const u16* __restrict__ qws, const u16* __restrict__ kws,
    const u16* __restrict__ vws, u16* __restrict__ ctx) {
  __shared__ u16 smem[4 * 64 * 64 + 256];  // Ks[2] | Vs[2] = 32 KiB; epilogue reuses
  u16* Ks0 = smem;                   // [buf][key][d] chunk-swizzled
  u16* Vs0 = smem + 2 * 64 * 64;     // [buf][d][pos] chunk-swizzled (permuted keys)
  const int t = threadIdx.x;
  const int w = t >> 6, l = t & 63, g = l >> 4, li = l & 15;
  // XCD-locality decode (R8-proven): per-XCD K/V set 3MB fits its L2
  const int n = blockIdx.x;
  const int xcd = n & 7, j = n >> 3;
  const int hb = xcd * 6 + (j >> 4);
  const int q0 = (j & 15) * 128;
  const int h = hb % NH, b = hb / NH;
  const size_t bh = (size_t)b * NH + h;
  const u16* qbp = qws + bh * SEQ * HD;
  const u16* kb = kws + bh * SEQ * HD;
  const u16* vb = vws + bh * HD * SEQ;

  // Q B-frags: B[k=d][n=q] = Q[q][d]; lane q = qt*16+li, k-chunk ks*32+g*8
  bf16x8 qf[2][2];
#pragma unroll
  for (int qt = 0; qt < 2; ++qt)
#pragma unroll
    for (int ks = 0; ks < 2; ++ks)
      qf[qt][ks] = *(const bf16x8*)(qbp + (size_t)(q0 + w * 32 + qt * 16 + li) * HD + ks * 32 + g * 8);
  asm volatile("s_waitcnt vmcnt(0)" ::: "memory");
  __builtin_amdgcn_sched_barrier(0);

  f32x4 acc[4][2];  // O^T tiles [dt][qt]: C row=d=dt*16+4g+i, col=q=qt*16+li
#pragma unroll
  for (int dt = 0; dt < 4; ++dt)
#pragma unroll
    for (int qt = 0; qt < 2; ++qt) acc[dt][qt] = {0.f, 0.f, 0.f, 0.f};
  float lrun[2] = {0.f, 0.f};  // per-lane partial; reduced at end

  // staging: wave w, inst j covers rows w*16+j*8 + (l>>3); chunk (l&7)^(l>>3)
  const int srow8 = l >> 3;
  const int skc = (l & 7) ^ srow8;
  const u16* gK = kb + (size_t)(w * 16 + srow8) * HD + skc * 8;
  const u16* gV = vb + (size_t)(w * 16 + srow8) * SEQ + skc * 8;

  constexpr int NT = SEQ / 64;

#define STAGE(kt_, buf_)                                                          \
  do {                                                                            \
    const int key0_ = (kt_) * 64;                                                 \
    GLD16(gK + (size_t)(key0_ + 0) * HD, &Ks0[(buf_) * 4096 + (w * 16 + 0) * 64]); \
    GLD16(gV + (size_t)0 * SEQ + key0_, &Vs0[(buf_) * 4096 + (w * 16 + 0) * 64]); \
    GLD16(gK + (size_t)(key0_ + 8) * HD, &Ks0[(buf_) * 4096 + (w * 16 + 8) * 64]); \
    GLD16(gV + (size_t)8 * SEQ + key0_, &Vs0[(buf_) * 4096 + (w * 16 + 8) * 64]); \
  } while (0)

  STAGE(0, 0);
  STAGE(1, 1);
  // tile 0 landed (8 outstanding -> <=4); tile 1's 4 stay in flight
  asm volatile("s_waitcnt vmcnt(4)" ::: "memory");
  __builtin_amdgcn_sched_barrier(0);
  __builtin_amdgcn_s_barrier();
  __builtin_amdgcn_sched_barrier(0);

  const f32x4 Z = {0.f, 0.f, 0.f, 0.f};

  for (int kt = 0; kt < NT; ++kt) {
    const int cur = kt & 1;
    const u16* KsC = Ks0 + cur * 4096;
    const u16* VsC = Vs0 + cur * 4096;

    // ---- S^T = K Q^T : A=K-frag, B=Q-frag (C=0 folded into first MFMA) ----
    f32x4 S[4][2];
    __builtin_amdgcn_s_setprio(1);
#pragma unroll
    for (int kb4 = 0; kb4 < 4; ++kb4) {
      bf16x8 kf0 = *(const bf16x8*)&KsC[(kb4 * 16 + li) * 64 + ((g ^ (li & 7)) * 8)];
      bf16x8 kf1 = *(const bf16x8*)&KsC[(kb4 * 16 + li) * 64 + (((4 + g) ^ (li & 7)) * 8)];
#pragma unroll
      for (int qt = 0; qt < 2; ++qt) {
        S[kb4][qt] = __builtin_amdgcn_mfma_f32_16x16x32_bf16(kf0, qf[qt][0], Z, 0, 0, 0);
        S[kb4][qt] = __builtin_amdgcn_mfma_f32_16x16x32_bf16(kf1, qf[qt][1], S[kb4][qt], 0, 0, 0);
      }
    }
    __builtin_amdgcn_s_setprio(0);

    // ---- P = exp2(S) (max-free), packed IN REGISTERS (no LDS round-trip) ----
    unsigned W[2][4][2];
#pragma unroll
    for (int qt = 0; qt < 2; ++qt) {
      float rs = 0.f;
#pragma unroll
      for (int kb4 = 0; kb4 < 4; ++kb4) {
        const float p0 = EXP2(S[kb4][qt][0]);
        const float p1 = EXP2(S[kb4][qt][1]);
        const float p2 = EXP2(S[kb4][qt][2]);
        const float p3 = EXP2(S[kb4][qt][3]);
        rs += (p0 + p1) + (p2 + p3);
        W[qt][kb4][0] = pk2bf(p0, p1);
        W[qt][kb4][1] = pk2bf(p2, p3);
      }
      lrun[qt] += rs;  // cross-lane reduce deferred to epilogue
    }

    // ---- O^T += V^T P^T: pf from S words (zero-shuffle); V-frag = ONE b128
    //      read at chunk (ks*4+g)^(d&7) thanks to permuted V storage ----
    __builtin_amdgcn_s_setprio(1);
#pragma unroll
    for (int ks = 0; ks < 2; ++ks) {
      union { uint4 u4; bf16x8 v; } pf0, pf1;
      pf0.u4.x = W[0][2 * ks][0];     pf0.u4.y = W[0][2 * ks][1];
      pf0.u4.z = W[0][2 * ks + 1][0]; pf0.u4.w = W[0][2 * ks + 1][1];
      pf1.u4.x = W[1][2 * ks][0];     pf1.u4.y = W[1][2 * ks][1];
      pf1.u4.z = W[1][2 * ks + 1][0]; pf1.u4.w = W[1][2 * ks + 1][1];
#pragma unroll
      for (int dt = 0; dt < 4; ++dt) {
        const int d = dt * 16 + li;
        bf16x8 vf = *(const bf16x8*)&VsC[d * 64 + (((ks * 4 + g) ^ (d & 7)) * 8)];
        acc[dt][0] = __builtin_amdgcn_mfma_f32_16x16x32_bf16(vf, pf0.v, acc[dt][0], 0, 0, 0);
        acc[dt][1] = __builtin_amdgcn_mfma_f32_16x16x32_bf16(vf, pf1.v, acc[dt][1], 0, 0, 0);
      }
    }
    __builtin_amdgcn_s_setprio(0);

    // ---- single per-tile sync: kt+1 landed; buf[cur] free; prefetch kt+2 ----
    if (kt + 1 < NT) {
      asm volatile("s_waitcnt vmcnt(0)" ::: "memory");
      __builtin_amdgcn_sched_barrier(0);
      __builtin_amdgcn_s_barrier();
      __builtin_amdgcn_sched_barrier(0);
      if (kt + 2 < NT) STAGE(kt + 2, cur);
    }
  }
#undef STAGE

  // ---- epilogue: cross-lane row-sum reduction (once), normalize, store ----
#pragma unroll
  for (int qt = 0; qt < 2; ++qt) {
    lrun[qt] += __shfl_xor(lrun[qt], 16);
    lrun[qt] += __shfl_xor(lrun[qt], 32);
  }
  float inv[2] = {1.f / lrun[0], 1.f / lrun[1]};
  __syncthreads();  // all waves done reading Ks/Vs; smem free for O staging
#pragma unroll
  for (int qt = 0; qt < 2; ++qt)
#pragma unroll
    for (int dt = 0; dt < 4; ++dt) {
      uint2 pk;
      pk.x = pk2bf(acc[dt][qt][0] * inv[qt], acc[dt][qt][1] * inv[qt]);
      pk.y = pk2bf(acc[dt][qt][2] * inv[qt], acc[dt][qt][3] * inv[qt]);
      *(uint2*)&smem[(w * 32 + qt * 16 + li) * 72 + dt * 16 + 4 * g] = pk;
    }
  __syncthreads();
  {
    const int r = t >> 3, c = (t & 7) * 8;
#pragma unroll
    for (int rd = 0; rd < 4; ++rd)
      *(uint4*)(ctx + ((size_t)b * SEQ + q0 + r + 32 * rd) * CDIM + h * HD + c) =
          *(const uint4*)&smem[(r + 32 * rd) * 72 + c];
  }
}

// ---------------------------------------------------------------------------
extern "C" void kernel_launch(void* const* d_in, const int* in_sizes, int n_in,
                              void* d_out, int out_size, void* d_ws, size_t ws_size,
                              hipStream_t stream) {
  (void)in_sizes; (void)n_in; (void)out_size; (void)ws_size;
  const float* x     = (const float*)d_in[0];
  const float* w_qkv = (const float*)d_in[1];
  const float* b_qkv = (const float*)d_in[2];
  const float* w_out = (const float*)d_in[3];
  const float* b_out = (const float*)d_in[4];
  float* out = (float*)d_out;

  // ws layout (u16 elements): xb | wqkvb | wob | Q | K | Vt | ctx  (~68 MB)
  u16* xb    = (u16*)d_ws;
  u16* wqkvb = xb + (size_t)MROWS * KD;
  u16* wob   = wqkvb + (size_t)3 * CDIM * KD;
  u16* qb    = wob + (size_t)CDIM * KD;
  const size_t QS = (size_t)BATCH * NH * SEQ * HD;
  u16* kb   = qb + QS;
  u16* vb   = kb + QS;
  u16* ctxb = vb + QS;

  hipLaunchKernelGGL(convert_bf16, dim3(2048), dim3(256), 0, stream,
                     x, xb, MROWS * KD / 4,
                     w_qkv, wqkvb, 3 * CDIM * KD / 4,
                     w_out, wob, CDIM * KD / 4);
  hipLaunchKernelGGL((gemm_bf16<0>), dim3((MROWS / 128) * (3 * CDIM / 128)), dim3(512), 0,
                     stream, xb, wqkvb, b_qkv, nullptr, qb, kb, vb);
  hipLaunchKernelGGL(attn_mfma, dim3(16 * NH * BATCH), dim3(256), 0, stream,
                     qb, kb, vb, ctxb);
  hipLaunchKernelGGL((gemm_bf16<1>), dim3((MROWS / 128) * (CDIM / 128)), dim3(512), 0,
                     stream, ctxb, wob, b_out, out, nullptr, nullptr, nullptr);
}

// Round 17
// 187.602 us; speedup vs baseline: 1.0791x; 1.0791x over previous
//
#include <hip/hip_runtime.h>
#include <math.h>

typedef __attribute__((ext_vector_type(8))) short bf16x8;   // 8 bf16 = 4 VGPRs
typedef __attribute__((ext_vector_type(4))) short bf16x4;   // 4 bf16 = 2 VGPRs
typedef __attribute__((ext_vector_type(4))) float f32x4;
typedef unsigned short u16;

namespace {
constexpr int BATCH = 4, SEQ = 2048, CDIM = 768, NH = 12, HD = 64;
constexpr int MROWS = BATCH * SEQ;  // 8192
constexpr int KD = CDIM;            // 768
// fold attention scale (1/8) * log2(e) into Q so softmax uses exp2 directly
constexpr float QSCALE = 0.125f * 1.44269504088896f;
}

__device__ __forceinline__ u16 f2bf(float f) {  // RNE float->bf16 (finite inputs)
  unsigned x = __float_as_uint(f);
  return (u16)((x + 0x7fffu + ((x >> 16) & 1u)) >> 16);
}

// packed f32x2 -> bf16x2 (lo=a, hi=b — verified by v5/v6/v7b passing kernels)
__device__ __forceinline__ unsigned pk2bf(float a, float b) {
  unsigned r;
  asm("v_cvt_pk_bf16_f32 %0, %1, %2" : "=v"(r) : "v"(a), "v"(b));
  return r;
}

// exp2 via builtin (R5/R6 A/B: builtin beats inline-asm — scheduler freedom)
#if defined(__has_builtin)
#if __has_builtin(__builtin_amdgcn_exp2f)
#define EXP2(x) __builtin_amdgcn_exp2f(x)
#endif
#endif
#ifndef EXP2
#define EXP2(x) exp2f(x)
#endif

// global_load_lds: 16B per lane, LDS dst = wave-uniform base + lane*16
#define GLD16(gp, lp)                                                        \
  __builtin_amdgcn_global_load_lds(                                          \
      (const __attribute__((address_space(1))) void*)(gp),                   \
      (__attribute__((address_space(3))) void*)(lp), 16, 0, 0)

// ---------------------------------------------------------------------------
// Pre-pass: fp32 -> bf16 for x, w_qkv, w_out
// ---------------------------------------------------------------------------
__global__ void convert_bf16(const float* __restrict__ x, u16* __restrict__ xb, int nx4,
                             const float* __restrict__ w1, u16* __restrict__ w1b, int n14,
                             const float* __restrict__ w2, u16* __restrict__ w2b, int n24) {
  const int stride = gridDim.x * blockDim.x;
  const int t0 = blockIdx.x * blockDim.x + threadIdx.x;
  for (int i = t0; i < nx4; i += stride) {
    float4 v = ((const float4*)x)[i];
    ushort4 o; o.x = f2bf(v.x); o.y = f2bf(v.y); o.z = f2bf(v.z); o.w = f2bf(v.w);
    ((ushort4*)xb)[i] = o;
  }
  for (int i = t0; i < n14; i += stride) {
    float4 v = ((const float4*)w1)[i];
    ushort4 o; o.x = f2bf(v.x); o.y = f2bf(v.y); o.z = f2bf(v.z); o.w = f2bf(v.w);
    ((ushort4*)w1b)[i] = o;
  }
  for (int i = t0; i < n24; i += stride) {
    float4 v = ((const float4*)w2)[i];
    ushort4 o; o.x = f2bf(v.x); o.y = f2bf(v.y); o.z = f2bf(v.z); o.w = f2bf(v.w);
    ((ushort4*)w2b)[i] = o;
  }
}

// ---------------------------------------------------------------------------
// bf16 MFMA GEMM (R7/R12 form — best across 5 structural variants; 16 w/CU).
// V epilogue stores keys PERMUTED within each 32-key group, pos(k) =
// 8*((k>>2)&3) + 4*((k>>4)&1) + (k&3), so attn's PV V-fragment is a single
// conflict-free b128 read (R16: bank conflicts 6.44M -> 147K, attn -6.2us).
// R17 refinement: permutation applied at the PATCH-WRITE index (pure constant
// re-index: col' = wm*32 + 8g + 4mi + i) so the store loop stays the original
// contiguous uint4 copy — removes R16's 2x-LDS-read store cost.
// ---------------------------------------------------------------------------
template <int MODE>
__global__ __launch_bounds__(512, 4) void gemm_bf16(
    const u16* __restrict__ A, const u16* __restrict__ Bw,
    const float* __restrict__ bias, float* __restrict__ outf,
    u16* __restrict__ qws, u16* __restrict__ kws, u16* __restrict__ vws) {
  __shared__ u16 smem[2 * 2 * 128 * 64];  // [buf][As|Bs], 64 KiB
  const int t = threadIdx.x;
  const int w = t >> 6, l = t & 63, g = l >> 4, li = l & 15;
  const int wm = w >> 1, wn = w & 1;  // 4 x 2 wave grid
  const int lin = blockIdx.x;
  const int rowb = ((lin & 7) << 3) | ((lin >> 3) & 7);
  const int colb = lin >> 6;
  const int row0 = rowb * 128, col0 = colb * 128;

  const int srow = w * 16 + (l >> 3);
  const int skc = (l & 7) ^ (l >> 3);
  const u16* gA = A + (size_t)(row0 + srow) * KD + skc * 8;
  const u16* gB = Bw + (size_t)(col0 + srow) * KD + skc * 8;

  f32x4 acc[2][4];
#pragma unroll
  for (int a = 0; a < 2; ++a)
#pragma unroll
    for (int c = 0; c < 4; ++c) acc[a][c] = {0.f, 0.f, 0.f, 0.f};

#define GSTAGE(kt_, buf_)                                                     \
  do {                                                                        \
    const int k0_ = (kt_) * 64;                                               \
    u16* As_ = smem + (buf_) * (2 * 128 * 64);                                \
    u16* Bs_ = As_ + 128 * 64;                                                \
    _Pragma("unroll")                                                         \
    for (int j = 0; j < 2; ++j) {                                             \
      GLD16(gA + (size_t)8 * j * KD + k0_, &As_[(w * 16 + 8 * j) * 64]);      \
      GLD16(gB + (size_t)8 * j * KD + k0_, &Bs_[(w * 16 + 8 * j) * 64]);      \
    }                                                                         \
  } while (0)

  constexpr int NK = KD / 64;  // 12
  GSTAGE(0, 0);
  GSTAGE(1, 1);
  asm volatile("s_waitcnt vmcnt(4)" ::: "memory");
  __builtin_amdgcn_sched_barrier(0);
  __builtin_amdgcn_s_barrier();
  __builtin_amdgcn_sched_barrier(0);

  for (int kt = 0; kt < NK; ++kt) {
    const int cur = kt & 1;
    const u16* AsC = smem + cur * (2 * 128 * 64);
    const u16* BsC = AsC + 128 * 64;

    bf16x8 af[2][2], bfr[4][2];
#pragma unroll
    for (int mi = 0; mi < 2; ++mi) {
      const int r = wm * 32 + mi * 16 + li;
#pragma unroll
      for (int ks = 0; ks < 2; ++ks)
        af[mi][ks] = *(const bf16x8*)&AsC[r * 64 + (((ks * 4 + g) ^ (li & 7)) * 8)];
    }
#pragma unroll
    for (int ni = 0; ni < 4; ++ni) {
      const int r = wn * 64 + ni * 16 + li;
#pragma unroll
      for (int ks = 0; ks < 2; ++ks)
        bfr[ni][ks] = *(const bf16x8*)&BsC[r * 64 + (((ks * 4 + g) ^ (li & 7)) * 8)];
    }
    __builtin_amdgcn_s_setprio(1);
#pragma unroll
    for (int ni = 0; ni < 4; ++ni)
#pragma unroll
      for (int mi = 0; mi < 2; ++mi) {
        acc[mi][ni] = __builtin_amdgcn_mfma_f32_16x16x32_bf16(af[mi][0], bfr[ni][0], acc[mi][ni], 0, 0, 0);
        acc[mi][ni] = __builtin_amdgcn_mfma_f32_16x16x32_bf16(af[mi][1], bfr[ni][1], acc[mi][ni], 0, 0, 0);
      }
    __builtin_amdgcn_s_setprio(0);

    if (kt + 1 < NK) {
      asm volatile("s_waitcnt vmcnt(0)" ::: "memory");
      __builtin_amdgcn_sched_barrier(0);
      __builtin_amdgcn_s_barrier();
      __builtin_amdgcn_sched_barrier(0);
      if (kt + 2 < NK) GSTAGE(kt + 2, cur);
    }
  }
#undef GSTAGE

  float bsr[4];
#pragma unroll
  for (int ni = 0; ni < 4; ++ni) bsr[ni] = bias[col0 + wn * 64 + ni * 16 + li];
  const int bidx = row0 >> 11;
  const int nseq0 = row0 & (SEQ - 1);

  __syncthreads();  // done with As/Bs; reuse smem for C staging

  if (MODE == 1) {
    float* Cf = (float*)smem;
#pragma unroll
    for (int p = 0; p < 4; ++p) {
      if (wm == p) {
#pragma unroll
        for (int mi = 0; mi < 2; ++mi)
#pragma unroll
          for (int ni = 0; ni < 4; ++ni)
#pragma unroll
            for (int i = 0; i < 4; ++i)
              Cf[(mi * 16 + 4 * g + i) * 132 + wn * 64 + ni * 16 + li] =
                  acc[mi][ni][i] + bsr[ni];
      }
      __syncthreads();
#pragma unroll
      for (int j = 0; j < 2; ++j) {
        const int fid = t + 512 * j;           // 0..1023
        const int r = fid >> 5, c4 = (fid & 31) * 4;
        *(float4*)(outf + (size_t)(row0 + p * 32 + r) * CDIM + col0 + c4) =
            *(const float4*)&Cf[r * 132 + c4];
      }
      __syncthreads();
    }
  } else {
#pragma unroll
    for (int hc = 0; hc < 2; ++hc) {
      const int nb = col0 + hc * 64;
      const int s = nb / CDIM;
      const int h = (nb % CDIM) / HD;
      if (wn == hc) {
        if (s < 2) {
          const float qs = (s == 0) ? QSCALE : 1.f;
#pragma unroll
          for (int mi = 0; mi < 2; ++mi)
#pragma unroll
            for (int ni = 0; ni < 4; ++ni)
#pragma unroll
              for (int i = 0; i < 4; ++i)
                smem[(wm * 32 + mi * 16 + 4 * g + i) * 72 + ni * 16 + li] =
                    f2bf((acc[mi][ni][i] + bsr[ni]) * qs);
        } else {
          // V: write PERMUTED within 32-key group — key k = mi*16+4g+i maps
          // to pos 8g+4mi+i ((k>>2)&3 = g, (k>>4)&1 = mi, k&3 = i).
#pragma unroll
          for (int mi = 0; mi < 2; ++mi)
#pragma unroll
            for (int ni = 0; ni < 4; ++ni)
#pragma unroll
              for (int i = 0; i < 4; ++i)
                smem[(ni * 16 + li) * 136 + wm * 32 + 8 * g + 4 * mi + i] =
                    f2bf(acc[mi][ni][i] + bsr[ni]);
        }
      }
      __syncthreads();
      if (s < 2) {
        u16* dst = (s == 0 ? qws : kws) + ((size_t)(bidx * NH + h) * SEQ + nseq0) * HD;
        const int r = t >> 3, c = (t & 7) * 8;   // r 0..63
#pragma unroll
        for (int rd = 0; rd < 2; ++rd)
          *(uint4*)(dst + (size_t)(r + 64 * rd) * HD + c) =
              *(const uint4*)&smem[(r + 64 * rd) * 72 + c];
      } else {
        // positions already permuted in the patch: plain contiguous copy
        u16* dst = vws + (size_t)(bidx * NH + h) * HD * SEQ + nseq0;
        const int d = t >> 4, c = (t & 15) * 8;  // d 0..31
#pragma unroll
        for (int rd = 0; rd < 2; ++rd)
          *(uint4*)(dst + (size_t)(d + 32 * rd) * SEQ + c) =
              *(const uint4*)&smem[(d + 32 * rd) * 136 + c];
      }
      __syncthreads();
    }
  }
}

// ---------------------------------------------------------------------------
// Flash attention v6.2 (UNCHANGED from R16 — measured best 61.9 us, bank
// conflicts 147K): in-register P via zero-shuffle bijection, single
// conflict-free b128 V read (permuted V storage), single barrier/tile,
// XCD-locality grid decode.
// ---------------------------------------------------------------------------
__global__ __launch_bounds__(256, 3) void attn_mfma(
    const u16* __restrict__ qws, const u16* __restrict__ kws,
    const u16* __restrict__ vws, u16* __restrict__ ctx) {
  __shared__ u16 smem[4 * 64 * 64 + 256];  // Ks[2] | Vs[2] = 32 KiB; epilogue reuses
  u16* Ks0 = smem;                   // [buf][key][d] chunk-swizzled
  u16* Vs0 = smem + 2 * 64 * 64;     // [buf][d][pos] chunk-swizzled (permuted keys)
  const int t = threadIdx.x;
  const int w = t >> 6, l = t & 63, g = l >> 4, li = l & 15;
  // XCD-locality decode (R8-proven): per-XCD K/V set 3MB fits its L2
  const int n = blockIdx.x;
  const int xcd = n & 7, j = n >> 3;
  const int hb = xcd * 6 + (j >> 4);
  const int q0 = (j & 15) * 128;
  const int h = hb % NH, b = hb / NH;
  const size_t bh = (size_t)b * NH + h;
  const u16* qbp = qws + bh * SEQ * HD;
  const u16* kb = kws + bh * SEQ * HD;
  const u16* vb = vws + bh * HD * SEQ;

  // Q B-frags: B[k=d][n=q] = Q[q][d]; lane q = qt*16+li, k-chunk ks*32+g*8
  bf16x8 qf[2][2];
#pragma unroll
  for (int qt = 0; qt < 2; ++qt)
#pragma unroll
    for (int ks = 0; ks < 2; ++ks)
      qf[qt][ks] = *(const bf16x8*)(qbp + (size_t)(q0 + w * 32 + qt * 16 + li) * HD + ks * 32 + g * 8);
  asm volatile("s_waitcnt vmcnt(0)" ::: "memory");
  __builtin_amdgcn_sched_barrier(0);

  f32x4 acc[4][2];  // O^T tiles [dt][qt]: C row=d=dt*16+4g+i, col=q=qt*16+li
#pragma unroll
  for (int dt = 0; dt < 4; ++dt)
#pragma unroll
    for (int qt = 0; qt < 2; ++qt) acc[dt][qt] = {0.f, 0.f, 0.f, 0.f};
  float lrun[2] = {0.f, 0.f};  // per-lane partial; reduced at end

  // staging: wave w, inst j covers rows w*16+j*8 + (l>>3); chunk (l&7)^(l>>3)
  const int srow8 = l >> 3;
  const int skc = (l & 7) ^ srow8;
  const u16* gK = kb + (size_t)(w * 16 + srow8) * HD + skc * 8;
  const u16* gV = vb + (size_t)(w * 16 + srow8) * SEQ + skc * 8;

  constexpr int NT = SEQ / 64;

#define STAGE(kt_, buf_)                                                          \
  do {                                                                            \
    const int key0_ = (kt_) * 64;                                                 \
    GLD16(gK + (size_t)(key0_ + 0) * HD, &Ks0[(buf_) * 4096 + (w * 16 + 0) * 64]); \
    GLD16(gV + (size_t)0 * SEQ + key0_, &Vs0[(buf_) * 4096 + (w * 16 + 0) * 64]); \
    GLD16(gK + (size_t)(key0_ + 8) * HD, &Ks0[(buf_) * 4096 + (w * 16 + 8) * 64]); \
    GLD16(gV + (size_t)8 * SEQ + key0_, &Vs0[(buf_) * 4096 + (w * 16 + 8) * 64]); \
  } while (0)

  STAGE(0, 0);
  STAGE(1, 1);
  // tile 0 landed (8 outstanding -> <=4); tile 1's 4 stay in flight
  asm volatile("s_waitcnt vmcnt(4)" ::: "memory");
  __builtin_amdgcn_sched_barrier(0);
  __builtin_amdgcn_s_barrier();
  __builtin_amdgcn_sched_barrier(0);

  const f32x4 Z = {0.f, 0.f, 0.f, 0.f};

  for (int kt = 0; kt < NT; ++kt) {
    const int cur = kt & 1;
    const u16* KsC = Ks0 + cur * 4096;
    const u16* VsC = Vs0 + cur * 4096;

    // ---- S^T = K Q^T : A=K-frag, B=Q-frag (C=0 folded into first MFMA) ----
    f32x4 S[4][2];
    __builtin_amdgcn_s_setprio(1);
#pragma unroll
    for (int kb4 = 0; kb4 < 4; ++kb4) {
      bf16x8 kf0 = *(const bf16x8*)&KsC[(kb4 * 16 + li) * 64 + ((g ^ (li & 7)) * 8)];
      bf16x8 kf1 = *(const bf16x8*)&KsC[(kb4 * 16 + li) * 64 + (((4 + g) ^ (li & 7)) * 8)];
#pragma unroll
      for (int qt = 0; qt < 2; ++qt) {
        S[kb4][qt] = __builtin_amdgcn_mfma_f32_16x16x32_bf16(kf0, qf[qt][0], Z, 0, 0, 0);
        S[kb4][qt] = __builtin_amdgcn_mfma_f32_16x16x32_bf16(kf1, qf[qt][1], S[kb4][qt], 0, 0, 0);
      }
    }
    __builtin_amdgcn_s_setprio(0);

    // ---- P = exp2(S) (max-free), packed IN REGISTERS (no LDS round-trip) ----
    unsigned W[2][4][2];
#pragma unroll
    for (int qt = 0; qt < 2; ++qt) {
      float rs = 0.f;
#pragma unroll
      for (int kb4 = 0; kb4 < 4; ++kb4) {
        const float p0 = EXP2(S[kb4][qt][0]);
        const float p1 = EXP2(S[kb4][qt][1]);
        const float p2 = EXP2(S[kb4][qt][2]);
        const float p3 = EXP2(S[kb4][qt][3]);
        rs += (p0 + p1) + (p2 + p3);
        W[qt][kb4][0] = pk2bf(p0, p1);
        W[qt][kb4][1] = pk2bf(p2, p3);
      }
      lrun[qt] += rs;  // cross-lane reduce deferred to epilogue
    }

    // ---- O^T += V^T P^T: pf from S words (zero-shuffle); V-frag = ONE b128
    //      read at chunk (ks*4+g)^(d&7) thanks to permuted V storage ----
    __builtin_amdgcn_s_setprio(1);
#pragma unroll
    for (int ks = 0; ks < 2; ++ks) {
      union { uint4 u4; bf16x8 v; } pf0, pf1;
      pf0.u4.x = W[0][2 * ks][0];     pf0.u4.y = W[0][2 * ks][1];
      pf0.u4.z = W[0][2 * ks + 1][0]; pf0.u4.w = W[0][2 * ks + 1][1];
      pf1.u4.x = W[1][2 * ks][0];     pf1.u4.y = W[1][2 * ks][1];
      pf1.u4.z = W[1][2 * ks + 1][0]; pf1.u4.w = W[1][2 * ks + 1][1];
#pragma unroll
      for (int dt = 0; dt < 4; ++dt) {
        const int d = dt * 16 + li;
        bf16x8 vf = *(const bf16x8*)&VsC[d * 64 + (((ks * 4 + g) ^ (d & 7)) * 8)];
        acc[dt][0] = __builtin_amdgcn_mfma_f32_16x16x32_bf16(vf, pf0.v, acc[dt][0], 0, 0, 0);
        acc[dt][1] = __builtin_amdgcn_mfma_f32_16x16x32_bf16(vf, pf1.v, acc[dt][1], 0, 0, 0);
      }
    }
    __builtin_amdgcn_s_setprio(0);

    // ---- single per-tile sync: kt+1 landed; buf[cur] free; prefetch kt+2 ----
    if (kt + 1 < NT) {
      asm volatile("s_waitcnt vmcnt(0)" ::: "memory");
      __builtin_amdgcn_sched_barrier(0);
      __builtin_amdgcn_s_barrier();
      __builtin_amdgcn_sched_barrier(0);
      if (kt + 2 < NT) STAGE(kt + 2, cur);
    }
  }
#undef STAGE

  // ---- epilogue: cross-lane row-sum reduction (once), normalize, store ----
#pragma unroll
  for (int qt = 0; qt < 2; ++qt) {
    lrun[qt] += __shfl_xor(lrun[qt], 16);
    lrun[qt] += __shfl_xor(lrun[qt], 32);
  }
  float inv[2] = {1.f / lrun[0], 1.f / lrun[1]};
  __syncthreads();  // all waves done reading Ks/Vs; smem free for O staging
#pragma unroll
  for (int qt = 0; qt < 2; ++qt)
#pragma unroll
    for (int dt = 0; dt < 4; ++dt) {
      uint2 pk;
      pk.x = pk2bf(acc[dt][qt][0] * inv[qt], acc[dt][qt][1] * inv[qt]);
      pk.y = pk2bf(acc[dt][qt][2] * inv[qt], acc[dt][qt][3] * inv[qt]);
      *(uint2*)&smem[(w * 32 + qt * 16 + li) * 72 + dt * 16 + 4 * g] = pk;
    }
  __syncthreads();
  {
    const int r = t >> 3, c = (t & 7) * 8;
#pragma unroll
    for (int rd = 0; rd < 4; ++rd)
      *(uint4*)(ctx + ((size_t)b * SEQ + q0 + r + 32 * rd) * CDIM + h * HD + c) =
          *(const uint4*)&smem[(r + 32 * rd) * 72 + c];
  }
}

// ---------------------------------------------------------------------------
extern "C" void kernel_launch(void* const* d_in, const int* in_sizes, int n_in,
                              void* d_out, int out_size, void* d_ws, size_t ws_size,
                              hipStream_t stream) {
  (void)in_sizes; (void)n_in; (void)out_size; (void)ws_size;
  const float* x     = (const float*)d_in[0];
  const float* w_qkv = (const float*)d_in[1];
  const float* b_qkv = (const float*)d_in[2];
  const float* w_out = (const float*)d_in[3];
  const float* b_out = (const float*)d_in[4];
  float* out = (float*)d_out;

  // ws layout (u16 elements): xb | wqkvb | wob | Q | K | Vt | ctx  (~68 MB)
  u16* xb    = (u16*)d_ws;
  u16* wqkvb = xb + (size_t)MROWS * KD;
  u16* wob   = wqkvb + (size_t)3 * CDIM * KD;
  u16* qb    = wob + (size_t)CDIM * KD;
  const size_t QS = (size_t)BATCH * NH * SEQ * HD;
  u16* kb   = qb + QS;
  u16* vb   = kb + QS;
  u16* ctxb = vb + QS;

  hipLaunchKernelGGL(convert_bf16, dim3(2048), dim3(256), 0, stream,
                     x, xb, MROWS * KD / 4,
                     w_qkv, wqkvb, 3 * CDIM * KD / 4,
                     w_out, wob, CDIM * KD / 4);
  hipLaunchKernelGGL((gemm_bf16<0>), dim3((MROWS / 128) * (3 * CDIM / 128)), dim3(512), 0,
                     stream, xb, wqkvb, b_qkv, nullptr, qb, kb, vb);
  hipLaunchKernelGGL(attn_mfma, dim3(16 * NH * BATCH), dim3(256), 0, stream,
                     qb, kb, vb, ctxb);
  hipLaunchKernelGGL((gemm_bf16<1>), dim3((MROWS / 128) * (CDIM / 128)), dim3(512), 0,
                     stream, ctxb, wob, b_out, out, nullptr, nullptr, nullptr);
}